// Round 5
// baseline (459.145 us; speedup 1.0000x reference)
//
#include <hip/hip_runtime.h>

#define N_NODES 150000
#define N_EDGES 2400000
#define N_GRAPHS 1024
#define F 32
#define EPSV 1e-5f

#define BS 256                                   // nodes per dst-bucket
#define NB ((N_NODES + BS - 1) / BS)             // 586 buckets
#define EB 4096                                  // edges per binning block
#define NEB ((N_EDGES + EB - 1) / EB)            // 586 blocks
#define EPT (EB / 256)                           // 16 edges per thread
#define NSTAT (N_GRAPHS * F)                     // 32768 per stat array

// bf16 helpers (RTN-even encode; decode via shift/mask)
__device__ __forceinline__ float bflo(unsigned int u) {
    union { unsigned int i; float f; } v; v.i = u << 16; return v.f;
}
__device__ __forceinline__ float bfhi(unsigned int u) {
    union { unsigned int i; float f; } v; v.i = u & 0xffff0000u; return v.f;
}
__device__ __forceinline__ unsigned int f2bf(float f) {
    union { float f; unsigned int i; } v; v.f = f;
    unsigned int r = v.i + 0x7fff + ((v.i >> 16) & 1);
    return r >> 16;
}

// ---------------------------------------------------------------------------
// K0: graph offsets from sorted batch; zero bucket histogram + stat arrays
// ---------------------------------------------------------------------------
__global__ void k_init(const int* __restrict__ batch, int* __restrict__ bucketCnt,
                       int* __restrict__ off, int* __restrict__ rowptr,
                       float* __restrict__ gstats) {
    int i = blockIdx.x * blockDim.x + threadIdx.x;
    if (i >= N_NODES) return;
    if (i < NB) bucketCnt[i] = 0;
    for (int j = i; j < 6 * NSTAT; j += N_NODES) gstats[j] = 0.f;
    if (i == 0) rowptr[N_NODES] = N_EDGES;
    int b = batch[i];
    if (i == 0) {
        for (int g = 0; g <= b; ++g) off[g] = 0;
    } else {
        int pb = batch[i - 1];
        for (int g = pb + 1; g <= b; ++g) off[g] = i;
    }
    if (i == N_NODES - 1) {
        for (int g = b + 1; g <= N_GRAPHS; ++g) off[g] = N_NODES;
    }
}

// ---------------------------------------------------------------------------
// K1: bucket histogram (LDS-aggregated)
// ---------------------------------------------------------------------------
__global__ __launch_bounds__(256) void k_bhist(const int* __restrict__ dst,
                                               int* __restrict__ bucketCnt) {
    __shared__ int h[NB];
    int t = threadIdx.x;
    for (int b = t; b < NB; b += 256) h[b] = 0;
    __syncthreads();
    int base = blockIdx.x * EB + t;
#pragma unroll
    for (int k = 0; k < EPT; ++k) {
        int e = base + k * 256;
        if (e < N_EDGES) atomicAdd(&h[dst[e] >> 8], 1);
    }
    __syncthreads();
    for (int b = t; b < NB; b += 256) {
        int c = h[b];
        if (c) atomicAdd(&bucketCnt[b], c);
    }
}

// ---------------------------------------------------------------------------
// K2: exclusive scan of bucket counts -> offsets + cursors
// ---------------------------------------------------------------------------
__global__ __launch_bounds__(256) void k_bscan(const int* __restrict__ bucketCnt,
                                               int* __restrict__ bucketOff,
                                               int* __restrict__ bucketCur) {
    __shared__ int sc[256];
    int t = threadIdx.x;
    int v[3];
    int s = 0;
#pragma unroll
    for (int k = 0; k < 3; ++k) {
        int i = t * 3 + k;
        v[k] = (i < NB) ? bucketCnt[i] : 0;
        s += v[k];
    }
    sc[t] = s;
    __syncthreads();
    for (int o = 1; o < 256; o <<= 1) {
        int x = (t >= o) ? sc[t - o] : 0;
        __syncthreads();
        sc[t] += x;
        __syncthreads();
    }
    int run = sc[t] - s;
#pragma unroll
    for (int k = 0; k < 3; ++k) {
        int i = t * 3 + k;
        if (i < NB) { bucketOff[i] = run; bucketCur[i] = run; }
        run += v[k];
    }
    if (t == 0) bucketOff[NB] = N_EDGES;
}

// ---------------------------------------------------------------------------
// K3: bin edges into buckets. key = (localdst << 18) | src
// ---------------------------------------------------------------------------
__global__ __launch_bounds__(256) void k_bin(const int* __restrict__ src,
                                             const int* __restrict__ dst,
                                             int* __restrict__ bucketCur,
                                             unsigned int* __restrict__ binned) {
    __shared__ int h[NB];
    __shared__ int gb[NB];
    int t = threadIdx.x;
    for (int b = t; b < NB; b += 256) h[b] = 0;
    __syncthreads();
    int base = blockIdx.x * EB + t;
    unsigned int key[EPT];
    int rk[EPT], bk[EPT];
#pragma unroll
    for (int k = 0; k < EPT; ++k) {
        int e = base + k * 256;
        if (e < N_EDGES) {
            int d = dst[e];
            int b = d >> 8;
            bk[k] = b;
            key[k] = ((unsigned int)(d & 255) << 18) | (unsigned int)src[e];
            rk[k] = atomicAdd(&h[b], 1);
        } else {
            bk[k] = -1;
        }
    }
    __syncthreads();
    for (int b = t; b < NB; b += 256) {
        int c = h[b];
        gb[b] = c ? atomicAdd(&bucketCur[b], c) : 0;
    }
    __syncthreads();
#pragma unroll
    for (int k = 0; k < EPT; ++k)
        if (bk[k] >= 0) binned[gb[bk[k]] + rk[k]] = key[k];
}

// ---------------------------------------------------------------------------
// K4: per-bucket CSR finalize: rowptr, dinv, xs = x*dinv (fused), csr fill
// ---------------------------------------------------------------------------
__global__ __launch_bounds__(256) void k_csr(const unsigned int* __restrict__ binned,
                                             const int* __restrict__ bucketOff,
                                             const float* __restrict__ x,
                                             int* __restrict__ rowptr,
                                             float* __restrict__ dinv,
                                             float* __restrict__ xs,
                                             int* __restrict__ csr) {
    __shared__ int lcnt[256];
    __shared__ int lpre[256];
    __shared__ int sc[256];
    int b = blockIdx.x, t = threadIdx.x;
    int e0 = bucketOff[b], e1 = bucketOff[b + 1];
    lcnt[t] = 0;
    __syncthreads();
    for (int e = e0 + t; e < e1; e += 256)
        atomicAdd(&lcnt[binned[e] >> 18], 1);
    __syncthreads();
    int v = lcnt[t];
    sc[t] = v;
    __syncthreads();
    for (int o = 1; o < 256; o <<= 1) {
        int x2 = (t >= o) ? sc[t - o] : 0;
        __syncthreads();
        sc[t] += x2;
        __syncthreads();
    }
    int excl = sc[t] - v;
    lpre[t] = excl;
    int gnode = b * BS + t;
    if (gnode < N_NODES) {
        rowptr[gnode] = e0 + excl;
        float dv = rsqrtf((float)v + 1.0f);
        dinv[gnode] = dv;
        xs[gnode * 3 + 0] = x[gnode * 3 + 0] * dv;
        xs[gnode * 3 + 1] = x[gnode * 3 + 1] * dv;
        xs[gnode * 3 + 2] = x[gnode * 3 + 2] * dv;
    }
    lcnt[t] = 0;
    __syncthreads();
    for (int e = e0 + t; e < e1; e += 256) {
        unsigned int key = binned[e];
        int ld = key >> 18;
        int pos = atomicAdd(&lcnt[ld], 1);
        csr[e0 + lpre[ld] + pos] = (int)(key & 0x3FFFFu);
    }
}

// ---------------------------------------------------------------------------
// K5a: layer-1 aggregate(3-wide, pre-scaled xs) + transform(3->32) + bias
// + per-(graph,feature) sum/sumsq stats epilogue. 8 threads/node.
// ---------------------------------------------------------------------------
__global__ __launch_bounds__(256) void k_gat3(
        const float* __restrict__ xs, const int* __restrict__ csr,
        const int* __restrict__ rowptr, const float* __restrict__ dinv,
        const int* __restrict__ batch,
        const float* __restrict__ W, const float* __restrict__ bias,
        float* __restrict__ gsum, float* __restrict__ gsq,
        float* __restrict__ y) {
    __shared__ float ssum[256], ssq[256];
    __shared__ int gbase_s;
    int t = threadIdx.x;
    ssum[t] = 0.f; ssq[t] = 0.f;
    if (t == 0) gbase_s = batch[blockIdx.x * 32];
    __syncthreads();

    int gid = blockIdx.x * 256 + t;
    int n = gid >> 3, c = gid & 7;
    bool act = (n < N_NODES);
    float4 o = {0.f, 0.f, 0.f, 0.f};
    if (act) {
        float z0 = xs[n * 3 + 0], z1 = xs[n * 3 + 1], z2 = xs[n * 3 + 2];
        int e0 = rowptr[n], e1 = rowptr[n + 1];
        for (int e = e0; e < e1; ++e) {
            int s = csr[e];
            z0 += xs[s * 3 + 0];
            z1 += xs[s * 3 + 1];
            z2 += xs[s * 3 + 2];
        }
        float dd = dinv[n];
        z0 *= dd; z1 *= dd; z2 *= dd;
        float4 w0 = ((const float4*)(W + 0 * F))[c];
        float4 w1 = ((const float4*)(W + 1 * F))[c];
        float4 w2 = ((const float4*)(W + 2 * F))[c];
        o = ((const float4*)bias)[c];
        o.x += z0 * w0.x + z1 * w1.x + z2 * w2.x;
        o.y += z0 * w0.y + z1 * w1.y + z2 * w2.y;
        o.z += z0 * w0.z + z1 * w1.z + z2 * w2.z;
        o.w += z0 * w0.w + z1 * w1.w + z2 * w2.w;
        ((float4*)y)[n * 8 + c] = o;
        int lg = batch[n] - gbase_s;
        if (lg < 8) {
            int base = lg * 32 + c * 4;
            atomicAdd(&ssum[base + 0], o.x); atomicAdd(&ssq[base + 0], o.x * o.x);
            atomicAdd(&ssum[base + 1], o.y); atomicAdd(&ssq[base + 1], o.y * o.y);
            atomicAdd(&ssum[base + 2], o.z); atomicAdd(&ssq[base + 2], o.z * o.z);
            atomicAdd(&ssum[base + 3], o.w); atomicAdd(&ssq[base + 3], o.w * o.w);
        } else {
            int base = batch[n] * F + c * 4;
            atomicAdd(&gsum[base + 0], o.x); atomicAdd(&gsq[base + 0], o.x * o.x);
            atomicAdd(&gsum[base + 1], o.y); atomicAdd(&gsq[base + 1], o.y * o.y);
            atomicAdd(&gsum[base + 2], o.z); atomicAdd(&gsq[base + 2], o.z * o.z);
            atomicAdd(&gsum[base + 3], o.w); atomicAdd(&gsq[base + 3], o.w * o.w);
        }
    }
    __syncthreads();
    int g = gbase_s + (t >> 5);
    if (g < N_GRAPHS) {
        float s = ssum[t], q = ssq[t];
        if (s != 0.f || q != 0.f) {
            atomicAdd(&gsum[g * F + (t & 31)], s);
            atomicAdd(&gsq[g * F + (t & 31)], q);
        }
    }
}

// ---------------------------------------------------------------------------
// K5b: aggregate(32-wide bf16 rows, self from xh) + transform(32->32) + bias
// + stats epilogue. 4 threads/node, 16B loads, 2x-unrolled edge loop.
// ---------------------------------------------------------------------------
__global__ __launch_bounds__(256) void k_gat32(
        const unsigned short* __restrict__ xh, const int* __restrict__ csr,
        const int* __restrict__ rowptr, const float* __restrict__ dinv,
        const int* __restrict__ batch,
        const float* __restrict__ W, const float* __restrict__ bias,
        float* __restrict__ gsum, float* __restrict__ gsq,
        float* __restrict__ y) {
    __shared__ float Ws[F * F];     // 4 KB
    __shared__ float bs[F];
    __shared__ float Zs[64 * 36];   // 9 KB
    __shared__ float ssum[256], ssq[256];
    __shared__ int gbase_s;
    int t = threadIdx.x;
    ((float4*)Ws)[t] = ((const float4*)W)[t];
    ssum[t] = 0.f; ssq[t] = 0.f;
    if (t < F) bs[t] = bias[t];
    if (t == 0) gbase_s = batch[blockIdx.x * 64];
    __syncthreads();

    int gid = blockIdx.x * 256 + t;
    int n = gid >> 2, c = gid & 3, ln = t >> 2;
    bool act = (n < N_NODES);
    float acc[8] = {0.f, 0.f, 0.f, 0.f, 0.f, 0.f, 0.f, 0.f};
    if (act) {
        const uint4* xr = (const uint4*)xh;  // row = 4 x 16B
        int e0 = rowptr[n], e1 = rowptr[n + 1];
        int e = e0;
        for (; e + 1 < e1; e += 2) {
            int s0 = csr[e], s1 = csr[e + 1];
            uint4 u0 = xr[s0 * 4 + c];
            uint4 u1 = xr[s1 * 4 + c];
            acc[0] += bflo(u0.x); acc[1] += bfhi(u0.x);
            acc[2] += bflo(u0.y); acc[3] += bfhi(u0.y);
            acc[4] += bflo(u0.z); acc[5] += bfhi(u0.z);
            acc[6] += bflo(u0.w); acc[7] += bfhi(u0.w);
            acc[0] += bflo(u1.x); acc[1] += bfhi(u1.x);
            acc[2] += bflo(u1.y); acc[3] += bfhi(u1.y);
            acc[4] += bflo(u1.z); acc[5] += bfhi(u1.z);
            acc[6] += bflo(u1.w); acc[7] += bfhi(u1.w);
        }
        if (e < e1) {
            int s0 = csr[e];
            uint4 u0 = xr[s0 * 4 + c];
            acc[0] += bflo(u0.x); acc[1] += bfhi(u0.x);
            acc[2] += bflo(u0.y); acc[3] += bfhi(u0.y);
            acc[4] += bflo(u0.z); acc[5] += bfhi(u0.z);
            acc[6] += bflo(u0.w); acc[7] += bfhi(u0.w);
        }
        // self loop: dd^2 * x[n] = dd * xh[n]
        uint4 us = ((const uint4*)xh)[n * 4 + c];
        acc[0] += bflo(us.x); acc[1] += bfhi(us.x);
        acc[2] += bflo(us.y); acc[3] += bfhi(us.y);
        acc[4] += bflo(us.z); acc[5] += bfhi(us.z);
        acc[6] += bflo(us.w); acc[7] += bfhi(us.w);
        float dd = dinv[n];
#pragma unroll
        for (int j = 0; j < 8; ++j) acc[j] *= dd;
    }
    *(float4*)&Zs[ln * 36 + c * 8]     = *(float4*)&acc[0];
    *(float4*)&Zs[ln * 36 + c * 8 + 4] = *(float4*)&acc[4];
    __syncthreads();

    if (act) {
        const float* zrow = &Zs[ln * 36];
        float4 o0 = ((const float4*)bs)[c * 2];
        float4 o1 = ((const float4*)bs)[c * 2 + 1];
#pragma unroll
        for (int k = 0; k < F; ++k) {
            float zk = zrow[k];
            float4 w0 = ((const float4*)&Ws[k * F])[c * 2];
            float4 w1 = ((const float4*)&Ws[k * F])[c * 2 + 1];
            o0.x += zk * w0.x; o0.y += zk * w0.y; o0.z += zk * w0.z; o0.w += zk * w0.w;
            o1.x += zk * w1.x; o1.y += zk * w1.y; o1.z += zk * w1.z; o1.w += zk * w1.w;
        }
        ((float4*)y)[n * 8 + c * 2]     = o0;
        ((float4*)y)[n * 8 + c * 2 + 1] = o1;
        int lg = batch[n] - gbase_s;
        if (lg < 8) {
            int base = lg * 32 + c * 8;
            atomicAdd(&ssum[base + 0], o0.x); atomicAdd(&ssq[base + 0], o0.x * o0.x);
            atomicAdd(&ssum[base + 1], o0.y); atomicAdd(&ssq[base + 1], o0.y * o0.y);
            atomicAdd(&ssum[base + 2], o0.z); atomicAdd(&ssq[base + 2], o0.z * o0.z);
            atomicAdd(&ssum[base + 3], o0.w); atomicAdd(&ssq[base + 3], o0.w * o0.w);
            atomicAdd(&ssum[base + 4], o1.x); atomicAdd(&ssq[base + 4], o1.x * o1.x);
            atomicAdd(&ssum[base + 5], o1.y); atomicAdd(&ssq[base + 5], o1.y * o1.y);
            atomicAdd(&ssum[base + 6], o1.z); atomicAdd(&ssq[base + 6], o1.z * o1.z);
            atomicAdd(&ssum[base + 7], o1.w); atomicAdd(&ssq[base + 7], o1.w * o1.w);
        } else {
            int base = batch[n] * F + c * 8;
            atomicAdd(&gsum[base + 0], o0.x); atomicAdd(&gsq[base + 0], o0.x * o0.x);
            atomicAdd(&gsum[base + 1], o0.y); atomicAdd(&gsq[base + 1], o0.y * o0.y);
            atomicAdd(&gsum[base + 2], o0.z); atomicAdd(&gsq[base + 2], o0.z * o0.z);
            atomicAdd(&gsum[base + 3], o0.w); atomicAdd(&gsq[base + 3], o0.w * o0.w);
            atomicAdd(&gsum[base + 4], o1.x); atomicAdd(&gsq[base + 4], o1.x * o1.x);
            atomicAdd(&gsum[base + 5], o1.y); atomicAdd(&gsq[base + 5], o1.y * o1.y);
            atomicAdd(&gsum[base + 6], o1.z); atomicAdd(&gsq[base + 6], o1.z * o1.z);
            atomicAdd(&gsum[base + 7], o1.w); atomicAdd(&gsq[base + 7], o1.w * o1.w);
        }
    }
    __syncthreads();
    int g = gbase_s + (t >> 5);
    if (g < N_GRAPHS) {
        float s = ssum[t], q = ssq[t];
        if (s != 0.f || q != 0.f) {
            atomicAdd(&gsum[g * F + (t & 31)], s);
            atomicAdd(&gsq[g * F + (t & 31)], q);
        }
    }
}

// ---------------------------------------------------------------------------
// K6: elementwise GraphNorm normalize (+ residual) + ReLU, single pass,
// stats from gsum/gsq. Emits fp32 out + bf16 dinv-pre-scaled xh.
// ---------------------------------------------------------------------------
template <bool RES>
__global__ __launch_bounds__(256) void k_norm(
        const float* agg, const float* res, const int* __restrict__ batch,
        const int* __restrict__ off,
        const float* __restrict__ gsum, const float* __restrict__ gsq,
        const float* __restrict__ gw, const float* __restrict__ gb,
        const float* __restrict__ gms, const float* __restrict__ dinv,
        unsigned short* __restrict__ xh, float* outp) {
    int gid = blockIdx.x * 256 + threadIdx.x;
    int n = gid >> 2, c = gid & 3;
    if (n >= N_NODES) return;
    int g = batch[n];
    float rc = 1.0f / (float)(off[g + 1] - off[g]);
    float dd = dinv[n];
    float4 a0 = ((const float4*)agg)[n * 8 + c * 2];
    float4 a1 = ((const float4*)agg)[n * 8 + c * 2 + 1];
    float av[8] = {a0.x, a0.y, a0.z, a0.w, a1.x, a1.y, a1.z, a1.w};
    float rv[8];
    if (RES) {
        float4 r0 = ((const float4*)res)[n * 8 + c * 2];
        float4 r1 = ((const float4*)res)[n * 8 + c * 2 + 1];
        rv[0] = r0.x; rv[1] = r0.y; rv[2] = r0.z; rv[3] = r0.w;
        rv[4] = r1.x; rv[5] = r1.y; rv[6] = r1.z; rv[7] = r1.w;
    }
    float o[8];
#pragma unroll
    for (int j = 0; j < 8; ++j) {
        int f = c * 8 + j;
        float m = gsum[g * F + f] * rc;
        float q = gsq[g * F + f] * rc;
        float mv = gms[f] * m;
        float var = q - mv * (2.f * m - mv);
        float rstd = rsqrtf(var + EPSV);
        float yv = (av[j] - mv) * gw[f] * rstd + gb[f];
        if (RES) yv += rv[j];
        o[j] = fmaxf(yv, 0.f);
    }
    ((float4*)outp)[n * 8 + c * 2]     = *(float4*)&o[0];
    ((float4*)outp)[n * 8 + c * 2 + 1] = *(float4*)&o[4];
    uint4 hp;
    hp.x = f2bf(o[0] * dd) | (f2bf(o[1] * dd) << 16);
    hp.y = f2bf(o[2] * dd) | (f2bf(o[3] * dd) << 16);
    hp.z = f2bf(o[4] * dd) | (f2bf(o[5] * dd) << 16);
    hp.w = f2bf(o[6] * dd) | (f2bf(o[7] * dd) << 16);
    ((uint4*)xh)[n * 4 + c] = hp;
}

// ---------------------------------------------------------------------------
// K7: final GraphNorm + residual + ReLU + mean-pool + 32x3 linear,
// single pass, stats precomputed. Block per graph.
// ---------------------------------------------------------------------------
__global__ __launch_bounds__(256) void k_gnfin(
        const float* __restrict__ agg, const float* __restrict__ res,
        const int* __restrict__ off,
        const float* __restrict__ gsum, const float* __restrict__ gsq,
        const float* __restrict__ gw, const float* __restrict__ gb,
        const float* __restrict__ lin_w, const float* __restrict__ lin_b,
        const float* __restrict__ gms, float* __restrict__ outp) {
    __shared__ float red[256];
    __shared__ float mv_s[F], sc_s[F], pooled_s[F];
    int g = blockIdx.x;
    int i0 = off[g], i1 = off[g + 1];
    float cnt = (float)(i1 - i0);
    int t = threadIdx.x;
    if (t < F) {
        float rc = 1.0f / cnt;
        float m = gsum[g * F + t] * rc;
        float q = gsq[g * F + t] * rc;
        float mv = gms[t] * m;
        float var = q - mv * (2.f * m - mv);
        mv_s[t] = mv;
        sc_s[t] = gw[t] * rsqrtf(var + EPSV);
    }
    __syncthreads();
    int f = t & 31, r0 = t >> 5;
    float w = sc_s[f], mv = mv_s[f], bb = gb[f];
    float ps = 0.f;
    for (int n = i0 + r0; n < i1; n += 8) {
        float yv = (agg[n * F + f] - mv) * w + bb + res[n * F + f];
        ps += fmaxf(yv, 0.f);
    }
    red[t] = ps; __syncthreads();
    if (t < 128) red[t] += red[t + 128]; __syncthreads();
    if (t < 64)  red[t] += red[t + 64];  __syncthreads();
    if (t < 32) { red[t] += red[t + 32]; pooled_s[t] = red[t] / cnt; }
    __syncthreads();
    if (t < 3) {
        float o = lin_b[t];
#pragma unroll
        for (int f2 = 0; f2 < F; ++f2) o += pooled_s[f2] * lin_w[f2 * 3 + t];
        outp[g * 3 + t] = o;
    }
}

// ---------------------------------------------------------------------------
extern "C" void kernel_launch(void* const* d_in, const int* in_sizes, int n_in,
                              void* d_out, int out_size, void* d_ws, size_t ws_size,
                              hipStream_t stream) {
    const float* x      = (const float*)d_in[0];
    const int*   ei     = (const int*)d_in[1];
    const int*   batch  = (const int*)d_in[2];
    const float* W1     = (const float*)d_in[3];
    const float* b1     = (const float*)d_in[4];
    const float* gn1w   = (const float*)d_in[5];
    const float* gn1b   = (const float*)d_in[6];
    const float* gn1ms  = (const float*)d_in[7];
    const float* W2     = (const float*)d_in[8];
    const float* b2     = (const float*)d_in[9];
    const float* gn2w   = (const float*)d_in[10];
    const float* gn2b   = (const float*)d_in[11];
    const float* gn2ms  = (const float*)d_in[12];
    const float* W3     = (const float*)d_in[13];
    const float* b3     = (const float*)d_in[14];
    const float* gn3w   = (const float*)d_in[15];
    const float* gn3b   = (const float*)d_in[16];
    const float* gn3ms  = (const float*)d_in[17];
    const float* lin_w  = (const float*)d_in[18];
    const float* lin_b  = (const float*)d_in[19];
    float* out = (float*)d_out;

    const int* srcp = ei;
    const int* dstp = ei + N_EDGES;

    char* ws = (char*)d_ws;
    size_t p = 0;
    auto alloc = [&](size_t bytes) {
        size_t r = p; p += (bytes + 511) & ~(size_t)511; return r;
    };
    int*   off       = (int*)  (ws + alloc(sizeof(int) * (N_GRAPHS + 1)));
    int*   bucketCnt = (int*)  (ws + alloc(sizeof(int) * NB));
    int*   bucketOff = (int*)  (ws + alloc(sizeof(int) * (NB + 1)));
    int*   bucketCur = (int*)  (ws + alloc(sizeof(int) * NB));
    int*   rowptr    = (int*)  (ws + alloc(sizeof(int) * (N_NODES + 1)));
    float* dinv      = (float*)(ws + alloc(sizeof(float) * N_NODES));
    float* xs        = (float*)(ws + alloc(sizeof(float) * N_NODES * 3));
    unsigned int* binned = (unsigned int*)(ws + alloc(sizeof(unsigned int) * N_EDGES));
    int*   csr       = (int*)  (ws + alloc(sizeof(int) * N_EDGES));
    float* A         = (float*)(ws + alloc(sizeof(float) * N_NODES * F));
    float* B         = (float*)(ws + alloc(sizeof(float) * N_NODES * F));
    float* gstats    = (float*)(ws + alloc(sizeof(float) * 6 * NSTAT));
    float* gsum1 = gstats,             * gsq1 = gstats + NSTAT;
    float* gsum2 = gstats + 2 * NSTAT, * gsq2 = gstats + 3 * NSTAT;
    float* gsum3 = gstats + 4 * NSTAT, * gsq3 = gstats + 5 * NSTAT;
    // xh aliases binned (dead after k_csr); both exactly 9.6 MB.
    unsigned short* xh = (unsigned short*)binned;
    (void)ws_size; (void)n_in; (void)in_sizes; (void)out_size;

    const int TB = 256;
    dim3 blk(TB);
    int ngrid  = (N_NODES + TB - 1) / TB;
    int ggrid8 = (N_NODES * 8 + TB - 1) / TB;
    int ggrid4 = (N_NODES * 4 + TB - 1) / TB;

    // CSR build via bucketed counting sort (+ dinv, xs fused into k_csr)
    k_init <<<ngrid, blk, 0, stream>>>(batch, bucketCnt, off, rowptr, gstats);
    k_bhist<<<NEB, blk, 0, stream>>>(dstp, bucketCnt);
    k_bscan<<<1, blk, 0, stream>>>(bucketCnt, bucketOff, bucketCur);
    k_bin  <<<NEB, blk, 0, stream>>>(srcp, dstp, bucketCur, binned);
    k_csr  <<<NB, blk, 0, stream>>>(binned, bucketOff, x, rowptr, dinv, xs, csr);

    // layer 1
    k_gat3 <<<ggrid8, blk, 0, stream>>>(xs, csr, rowptr, dinv, batch, W1, b1,
                                        gsum1, gsq1, A);
    k_norm<false><<<ggrid4, blk, 0, stream>>>(A, nullptr, batch, off, gsum1, gsq1,
                                              gn1w, gn1b, gn1ms, dinv, xh, A);
    // layer 2
    k_gat32<<<ggrid4, blk, 0, stream>>>(xh, csr, rowptr, dinv, batch, W2, b2,
                                        gsum2, gsq2, B);
    k_norm<true><<<ggrid4, blk, 0, stream>>>(B, A, batch, off, gsum2, gsq2,
                                             gn2w, gn2b, gn2ms, dinv, xh, B);
    // layer 3
    k_gat32<<<ggrid4, blk, 0, stream>>>(xh, csr, rowptr, dinv, batch, W3, b3,
                                        gsum3, gsq3, A);
    k_gnfin<<<N_GRAPHS, blk, 0, stream>>>(A, B, off, gsum3, gsq3,
                                          gn3w, gn3b, lin_w, lin_b, gn3ms, out);
}

// Round 7
// 396.563 us; speedup vs baseline: 1.1578x; 1.1578x over previous
//
#include <hip/hip_runtime.h>

#define N_NODES 150000
#define N_EDGES 2400000
#define N_GRAPHS 1024
#define F 32
#define EPSV 1e-5f

#define BS 256                                   // nodes per dst-bucket
#define NB ((N_NODES + BS - 1) / BS)             // 586 buckets
#define EB 4096                                  // edges per binning block
#define NEB ((N_EDGES + EB - 1) / EB)            // 586 blocks
#define EPT (EB / 256)                           // 16 edges per thread

typedef float floatx4 __attribute__((ext_vector_type(4)));  // native vec for NT builtins

// bf16 helpers (RTN-even encode; decode via shift/mask)
__device__ __forceinline__ float bflo(unsigned int u) {
    union { unsigned int i; float f; } v; v.i = u << 16; return v.f;
}
__device__ __forceinline__ float bfhi(unsigned int u) {
    union { unsigned int i; float f; } v; v.i = u & 0xffff0000u; return v.f;
}
__device__ __forceinline__ unsigned int f2bf(float f) {
    union { float f; unsigned int i; } v; v.f = f;
    unsigned int r = v.i + 0x7fff + ((v.i >> 16) & 1);
    return r >> 16;
}

// ---------------------------------------------------------------------------
// K0: graph offsets from sorted batch; zero bucket histogram
// ---------------------------------------------------------------------------
__global__ void k_init(const int* __restrict__ batch, int* __restrict__ bucketCnt,
                       int* __restrict__ off, int* __restrict__ rowptr) {
    int i = blockIdx.x * blockDim.x + threadIdx.x;
    if (i >= N_NODES) return;
    if (i < NB) bucketCnt[i] = 0;
    if (i == 0) rowptr[N_NODES] = N_EDGES;
    int b = batch[i];
    if (i == 0) {
        for (int g = 0; g <= b; ++g) off[g] = 0;
    } else {
        int pb = batch[i - 1];
        for (int g = pb + 1; g <= b; ++g) off[g] = i;
    }
    if (i == N_NODES - 1) {
        for (int g = b + 1; g <= N_GRAPHS; ++g) off[g] = N_NODES;
    }
}

// ---------------------------------------------------------------------------
// K1: bucket histogram (LDS-aggregated; addresses well-distributed -> no
// same-address cliffs like the R5 stats epilogue)
// ---------------------------------------------------------------------------
__global__ __launch_bounds__(256) void k_bhist(const int* __restrict__ dst,
                                               int* __restrict__ bucketCnt) {
    __shared__ int h[NB];
    int t = threadIdx.x;
    for (int b = t; b < NB; b += 256) h[b] = 0;
    __syncthreads();
    int base = blockIdx.x * EB + t;
#pragma unroll
    for (int k = 0; k < EPT; ++k) {
        int e = base + k * 256;
        if (e < N_EDGES) atomicAdd(&h[dst[e] >> 8], 1);
    }
    __syncthreads();
    for (int b = t; b < NB; b += 256) {
        int c = h[b];
        if (c) atomicAdd(&bucketCnt[b], c);
    }
}

// ---------------------------------------------------------------------------
// K2: exclusive scan of bucket counts -> offsets + cursors
// ---------------------------------------------------------------------------
__global__ __launch_bounds__(256) void k_bscan(const int* __restrict__ bucketCnt,
                                               int* __restrict__ bucketOff,
                                               int* __restrict__ bucketCur) {
    __shared__ int sc[256];
    int t = threadIdx.x;
    int v[3];
    int s = 0;
#pragma unroll
    for (int k = 0; k < 3; ++k) {
        int i = t * 3 + k;
        v[k] = (i < NB) ? bucketCnt[i] : 0;
        s += v[k];
    }
    sc[t] = s;
    __syncthreads();
    for (int o = 1; o < 256; o <<= 1) {
        int x = (t >= o) ? sc[t - o] : 0;
        __syncthreads();
        sc[t] += x;
        __syncthreads();
    }
    int run = sc[t] - s;
#pragma unroll
    for (int k = 0; k < 3; ++k) {
        int i = t * 3 + k;
        if (i < NB) { bucketOff[i] = run; bucketCur[i] = run; }
        run += v[k];
    }
    if (t == 0) bucketOff[NB] = N_EDGES;
}

// ---------------------------------------------------------------------------
// K3: bin edges into buckets. key = (localdst << 18) | src
// ---------------------------------------------------------------------------
__global__ __launch_bounds__(256) void k_bin(const int* __restrict__ src,
                                             const int* __restrict__ dst,
                                             int* __restrict__ bucketCur,
                                             unsigned int* __restrict__ binned) {
    __shared__ int h[NB];
    __shared__ int gb[NB];
    int t = threadIdx.x;
    for (int b = t; b < NB; b += 256) h[b] = 0;
    __syncthreads();
    int base = blockIdx.x * EB + t;
    unsigned int key[EPT];
    int rk[EPT], bk[EPT];
#pragma unroll
    for (int k = 0; k < EPT; ++k) {
        int e = base + k * 256;
        if (e < N_EDGES) {
            int d = dst[e];
            int b = d >> 8;
            bk[k] = b;
            key[k] = ((unsigned int)(d & 255) << 18) | (unsigned int)src[e];
            rk[k] = atomicAdd(&h[b], 1);
        } else {
            bk[k] = -1;
        }
    }
    __syncthreads();
    for (int b = t; b < NB; b += 256) {
        int c = h[b];
        gb[b] = c ? atomicAdd(&bucketCur[b], c) : 0;
    }
    __syncthreads();
#pragma unroll
    for (int k = 0; k < EPT; ++k)
        if (bk[k] >= 0) binned[gb[bk[k]] + rk[k]] = key[k];
}

// ---------------------------------------------------------------------------
// K4: per-bucket CSR finalize: rowptr, dinv, xs = x*dinv (fused), csr fill
// ---------------------------------------------------------------------------
__global__ __launch_bounds__(256) void k_csr(const unsigned int* __restrict__ binned,
                                             const int* __restrict__ bucketOff,
                                             const float* __restrict__ x,
                                             int* __restrict__ rowptr,
                                             float* __restrict__ dinv,
                                             float* __restrict__ xs,
                                             int* __restrict__ csr) {
    __shared__ int lcnt[256];
    __shared__ int lpre[256];
    __shared__ int sc[256];
    int b = blockIdx.x, t = threadIdx.x;
    int e0 = bucketOff[b], e1 = bucketOff[b + 1];
    lcnt[t] = 0;
    __syncthreads();
    for (int e = e0 + t; e < e1; e += 256)
        atomicAdd(&lcnt[binned[e] >> 18], 1);
    __syncthreads();
    int v = lcnt[t];
    sc[t] = v;
    __syncthreads();
    for (int o = 1; o < 256; o <<= 1) {
        int x2 = (t >= o) ? sc[t - o] : 0;
        __syncthreads();
        sc[t] += x2;
        __syncthreads();
    }
    int excl = sc[t] - v;
    lpre[t] = excl;
    int gnode = b * BS + t;
    if (gnode < N_NODES) {
        rowptr[gnode] = e0 + excl;
        float dv = rsqrtf((float)v + 1.0f);
        dinv[gnode] = dv;
        xs[gnode * 3 + 0] = x[gnode * 3 + 0] * dv;
        xs[gnode * 3 + 1] = x[gnode * 3 + 1] * dv;
        xs[gnode * 3 + 2] = x[gnode * 3 + 2] * dv;
    }
    lcnt[t] = 0;
    __syncthreads();
    for (int e = e0 + t; e < e1; e += 256) {
        unsigned int key = binned[e];
        int ld = key >> 18;
        int pos = atomicAdd(&lcnt[ld], 1);
        csr[e0 + lpre[ld] + pos] = (int)(key & 0x3FFFFu);
    }
}

// ---------------------------------------------------------------------------
// K5a: layer-1 aggregate(3-wide, pre-scaled xs) + transform(3->32) + bias.
// 8 threads/node. Lean (no stats).
// ---------------------------------------------------------------------------
__global__ __launch_bounds__(256) void k_gat3(
        const float* __restrict__ xs, const int* __restrict__ csr,
        const int* __restrict__ rowptr, const float* __restrict__ dinv,
        const float* __restrict__ W, const float* __restrict__ bias,
        float* __restrict__ y) {
    int gid = blockIdx.x * 256 + threadIdx.x;
    int n = gid >> 3, c = gid & 7;
    if (n >= N_NODES) return;
    float z0 = xs[n * 3 + 0], z1 = xs[n * 3 + 1], z2 = xs[n * 3 + 2];
    int e0 = rowptr[n], e1 = rowptr[n + 1];
    for (int e = e0; e < e1; ++e) {
        int s = __builtin_nontemporal_load(csr + e);
        z0 += xs[s * 3 + 0];
        z1 += xs[s * 3 + 1];
        z2 += xs[s * 3 + 2];
    }
    float dd = dinv[n];
    z0 *= dd; z1 *= dd; z2 *= dd;
    float4 w0 = ((const float4*)(W + 0 * F))[c];
    float4 w1 = ((const float4*)(W + 1 * F))[c];
    float4 w2 = ((const float4*)(W + 2 * F))[c];
    float4 o  = ((const float4*)bias)[c];
    o.x += z0 * w0.x + z1 * w1.x + z2 * w2.x;
    o.y += z0 * w0.y + z1 * w1.y + z2 * w2.y;
    o.z += z0 * w0.z + z1 * w1.z + z2 * w2.z;
    o.w += z0 * w0.w + z1 * w1.w + z2 * w2.w;
    ((float4*)y)[n * 8 + c] = o;
}

// ---------------------------------------------------------------------------
// K5b: aggregate(32-wide bf16 rows, self from xh) + transform(32->32) + bias.
// 4 threads/node, 16B loads. NT loads for csr (one-touch stream) and NT
// stores for y (streamed output) so the 9.6 MB xh gather set keeps L2.
// ---------------------------------------------------------------------------
__global__ __launch_bounds__(256) void k_gat32(
        const unsigned short* __restrict__ xh, const int* __restrict__ csr,
        const int* __restrict__ rowptr, const float* __restrict__ dinv,
        const float* __restrict__ W, const float* __restrict__ bias,
        float* __restrict__ y) {
    __shared__ float Ws[F * F];     // 4 KB
    __shared__ float bs[F];
    __shared__ float Zs[64 * 36];   // 9 KB
    int t = threadIdx.x;
    ((float4*)Ws)[t] = ((const float4*)W)[t];
    if (t < F) bs[t] = bias[t];
    __syncthreads();

    int gid = blockIdx.x * 256 + t;
    int n = gid >> 2, c = gid & 3, ln = t >> 2;
    bool act = (n < N_NODES);
    float acc[8] = {0.f, 0.f, 0.f, 0.f, 0.f, 0.f, 0.f, 0.f};
    if (act) {
        const uint4* xr = (const uint4*)xh;  // row = 4 x 16B
        // self loop: dd^2 * x[n] = dd * xh[n]
        uint4 us = xr[n * 4 + c];
        acc[0] = bflo(us.x); acc[1] = bfhi(us.x);
        acc[2] = bflo(us.y); acc[3] = bfhi(us.y);
        acc[4] = bflo(us.z); acc[5] = bfhi(us.z);
        acc[6] = bflo(us.w); acc[7] = bfhi(us.w);
        int e0 = rowptr[n], e1 = rowptr[n + 1];
        int e = e0;
        for (; e + 1 < e1; e += 2) {
            int s0 = __builtin_nontemporal_load(csr + e);
            int s1 = __builtin_nontemporal_load(csr + e + 1);
            uint4 u0 = xr[s0 * 4 + c];
            uint4 u1 = xr[s1 * 4 + c];
            acc[0] += bflo(u0.x); acc[1] += bfhi(u0.x);
            acc[2] += bflo(u0.y); acc[3] += bfhi(u0.y);
            acc[4] += bflo(u0.z); acc[5] += bfhi(u0.z);
            acc[6] += bflo(u0.w); acc[7] += bfhi(u0.w);
            acc[0] += bflo(u1.x); acc[1] += bfhi(u1.x);
            acc[2] += bflo(u1.y); acc[3] += bfhi(u1.y);
            acc[4] += bflo(u1.z); acc[5] += bfhi(u1.z);
            acc[6] += bflo(u1.w); acc[7] += bfhi(u1.w);
        }
        if (e < e1) {
            int s0 = __builtin_nontemporal_load(csr + e);
            uint4 u0 = xr[s0 * 4 + c];
            acc[0] += bflo(u0.x); acc[1] += bfhi(u0.x);
            acc[2] += bflo(u0.y); acc[3] += bfhi(u0.y);
            acc[4] += bflo(u0.z); acc[5] += bfhi(u0.z);
            acc[6] += bflo(u0.w); acc[7] += bfhi(u0.w);
        }
        float dd = dinv[n];
#pragma unroll
        for (int j = 0; j < 8; ++j) acc[j] *= dd;
    }
    *(float4*)&Zs[ln * 36 + c * 8]     = *(float4*)&acc[0];
    *(float4*)&Zs[ln * 36 + c * 8 + 4] = *(float4*)&acc[4];
    __syncthreads();

    if (act) {
        const float* zrow = &Zs[ln * 36];
        float4 o0 = ((const float4*)bs)[c * 2];
        float4 o1 = ((const float4*)bs)[c * 2 + 1];
#pragma unroll
        for (int k = 0; k < F; ++k) {
            float zk = zrow[k];
            float4 w0 = ((const float4*)&Ws[k * F])[c * 2];
            float4 w1 = ((const float4*)&Ws[k * F])[c * 2 + 1];
            o0.x += zk * w0.x; o0.y += zk * w0.y; o0.z += zk * w0.z; o0.w += zk * w0.w;
            o1.x += zk * w1.x; o1.y += zk * w1.y; o1.z += zk * w1.z; o1.w += zk * w1.w;
        }
        floatx4 v0 = {o0.x, o0.y, o0.z, o0.w};
        floatx4 v1 = {o1.x, o1.y, o1.z, o1.w};
        __builtin_nontemporal_store(v0, (floatx4*)y + n * 8 + c * 2);
        __builtin_nontemporal_store(v1, (floatx4*)y + n * 8 + c * 2 + 1);
    }
}

// ---------------------------------------------------------------------------
// K6: GraphNorm, block per graph, TWO passes (stats via sum/sumsq in ONE read
// pass; normalize pass re-reads the ~19KB graph slice L2-hot). In-place
// capable. Emits fp32 out + (WXH) bf16 dinv-pre-scaled xh.
// ---------------------------------------------------------------------------
template <bool RES, bool WXH>
__global__ __launch_bounds__(256) void k_gn2(
        const float* agg, const float* res, const int* __restrict__ off,
        const float* __restrict__ gw, const float* __restrict__ gb,
        const float* __restrict__ gms, const float* __restrict__ dinv,
        unsigned short* __restrict__ xh, float* outp) {
    __shared__ float red1[256], red2[256];
    __shared__ float mv_s[F], sc_s[F];
    int g = blockIdx.x;
    int i0 = off[g], i1 = off[g + 1];
    float rc = 1.0f / (float)(i1 - i0);
    int t = threadIdx.x;
    int f = t & 31, r0 = t >> 5;

    float s = 0.f, q = 0.f;
    for (int n = i0 + r0; n < i1; n += 8) {
        float v = agg[n * F + f];
        s += v; q += v * v;
    }
    red1[t] = s; red2[t] = q; __syncthreads();
    if (t < 128) { red1[t] += red1[t + 128]; red2[t] += red2[t + 128]; } __syncthreads();
    if (t < 64)  { red1[t] += red1[t + 64];  red2[t] += red2[t + 64];  } __syncthreads();
    if (t < 32) {
        float sm = (red1[t] + red1[t + 32]) * rc;
        float sq = (red2[t] + red2[t + 32]) * rc;
        float mv = gms[t] * sm;
        float var = sq - mv * (2.f * sm - mv);
        mv_s[t] = mv;
        sc_s[t] = gw[t] * rsqrtf(var + EPSV);
    }
    __syncthreads();

    float w = sc_s[f], mv = mv_s[f], bb = gb[f];
    for (int n = i0 + r0; n < i1; n += 8) {
        float y = (agg[n * F + f] - mv) * w + bb;
        if (RES) y += res[n * F + f];
        y = fmaxf(y, 0.f);
        outp[n * F + f] = y;
        if (WXH) xh[n * F + f] = (unsigned short)f2bf(y * dinv[n]);
    }
}

// ---------------------------------------------------------------------------
// K7: final GraphNorm + residual + ReLU + mean-pool + 32x3 linear; stats
// computed in-kernel (single read pass), pooling pass L2-hot. Block per graph.
// ---------------------------------------------------------------------------
__global__ __launch_bounds__(256) void k_gnfin(
        const float* __restrict__ agg, const float* __restrict__ res,
        const int* __restrict__ off,
        const float* __restrict__ gw, const float* __restrict__ gb,
        const float* __restrict__ gms,
        const float* __restrict__ lin_w, const float* __restrict__ lin_b,
        float* __restrict__ outp) {
    __shared__ float red1[256], red2[256];
    __shared__ float mv_s[F], sc_s[F], pooled_s[F];
    int g = blockIdx.x;
    int i0 = off[g], i1 = off[g + 1];
    float cnt = (float)(i1 - i0);
    float rc = 1.0f / cnt;
    int t = threadIdx.x;
    int f = t & 31, r0 = t >> 5;

    float s = 0.f, q = 0.f;
    for (int n = i0 + r0; n < i1; n += 8) {
        float v = agg[n * F + f];
        s += v; q += v * v;
    }
    red1[t] = s; red2[t] = q; __syncthreads();
    if (t < 128) { red1[t] += red1[t + 128]; red2[t] += red2[t + 128]; } __syncthreads();
    if (t < 64)  { red1[t] += red1[t + 64];  red2[t] += red2[t + 64];  } __syncthreads();
    if (t < 32) {
        float sm = (red1[t] + red1[t + 32]) * rc;
        float sq = (red2[t] + red2[t + 32]) * rc;
        float mv = gms[t] * sm;
        float var = sq - mv * (2.f * sm - mv);
        mv_s[t] = mv;
        sc_s[t] = gw[t] * rsqrtf(var + EPSV);
    }
    __syncthreads();

    float w = sc_s[f], mv = mv_s[f], bb = gb[f];
    float ps = 0.f;
    for (int n = i0 + r0; n < i1; n += 8) {
        float yv = (agg[n * F + f] - mv) * w + bb + res[n * F + f];
        ps += fmaxf(yv, 0.f);
    }
    __syncthreads();
    red1[t] = ps; __syncthreads();
    if (t < 128) red1[t] += red1[t + 128]; __syncthreads();
    if (t < 64)  red1[t] += red1[t + 64];  __syncthreads();
    if (t < 32) { red1[t] += red1[t + 32]; pooled_s[t] = red1[t] * rc; }
    __syncthreads();
    if (t < 3) {
        float o = lin_b[t];
#pragma unroll
        for (int f2 = 0; f2 < F; ++f2) o += pooled_s[f2] * lin_w[f2 * 3 + t];
        outp[g * 3 + t] = o;
    }
}

// ---------------------------------------------------------------------------
extern "C" void kernel_launch(void* const* d_in, const int* in_sizes, int n_in,
                              void* d_out, int out_size, void* d_ws, size_t ws_size,
                              hipStream_t stream) {
    const float* x      = (const float*)d_in[0];
    const int*   ei     = (const int*)d_in[1];
    const int*   batch  = (const int*)d_in[2];
    const float* W1     = (const float*)d_in[3];
    const float* b1     = (const float*)d_in[4];
    const float* gn1w   = (const float*)d_in[5];
    const float* gn1b   = (const float*)d_in[6];
    const float* gn1ms  = (const float*)d_in[7];
    const float* W2     = (const float*)d_in[8];
    const float* b2     = (const float*)d_in[9];
    const float* gn2w   = (const float*)d_in[10];
    const float* gn2b   = (const float*)d_in[11];
    const float* gn2ms  = (const float*)d_in[12];
    const float* W3     = (const float*)d_in[13];
    const float* b3     = (const float*)d_in[14];
    const float* gn3w   = (const float*)d_in[15];
    const float* gn3b   = (const float*)d_in[16];
    const float* gn3ms  = (const float*)d_in[17];
    const float* lin_w  = (const float*)d_in[18];
    const float* lin_b  = (const float*)d_in[19];
    float* out = (float*)d_out;

    const int* srcp = ei;
    const int* dstp = ei + N_EDGES;

    char* ws = (char*)d_ws;
    size_t p = 0;
    auto alloc = [&](size_t bytes) {
        size_t r = p; p += (bytes + 511) & ~(size_t)511; return r;
    };
    int*   off       = (int*)  (ws + alloc(sizeof(int) * (N_GRAPHS + 1)));
    int*   bucketCnt = (int*)  (ws + alloc(sizeof(int) * NB));
    int*   bucketOff = (int*)  (ws + alloc(sizeof(int) * (NB + 1)));
    int*   bucketCur = (int*)  (ws + alloc(sizeof(int) * NB));
    int*   rowptr    = (int*)  (ws + alloc(sizeof(int) * (N_NODES + 1)));
    float* dinv      = (float*)(ws + alloc(sizeof(float) * N_NODES));
    float* xs        = (float*)(ws + alloc(sizeof(float) * N_NODES * 3));
    unsigned int* binned = (unsigned int*)(ws + alloc(sizeof(unsigned int) * N_EDGES));
    int*   csr       = (int*)  (ws + alloc(sizeof(int) * N_EDGES));
    float* A         = (float*)(ws + alloc(sizeof(float) * N_NODES * F));
    float* B         = (float*)(ws + alloc(sizeof(float) * N_NODES * F));
    // xh aliases binned (dead after k_csr); both exactly 9.6 MB.
    unsigned short* xh = (unsigned short*)binned;
    (void)ws_size; (void)n_in; (void)in_sizes; (void)out_size;

    const int TB = 256;
    dim3 blk(TB);
    int ngrid  = (N_NODES + TB - 1) / TB;
    int ggrid8 = (N_NODES * 8 + TB - 1) / TB;
    int ggrid4 = (N_NODES * 4 + TB - 1) / TB;

    // CSR build via bucketed counting sort (+ dinv, xs fused into k_csr)
    k_init <<<ngrid, blk, 0, stream>>>(batch, bucketCnt, off, rowptr);
    k_bhist<<<NEB, blk, 0, stream>>>(dstp, bucketCnt);
    k_bscan<<<1, blk, 0, stream>>>(bucketCnt, bucketOff, bucketCur);
    k_bin  <<<NEB, blk, 0, stream>>>(srcp, dstp, bucketCur, binned);
    k_csr  <<<NB, blk, 0, stream>>>(binned, bucketOff, x, rowptr, dinv, xs, csr);

    // layer 1: gather+transform -> A ; GN in-place -> x1=A (+ bf16 xh)
    k_gat3 <<<ggrid8, blk, 0, stream>>>(xs, csr, rowptr, dinv, W1, b1, A);
    k_gn2<false, true><<<N_GRAPHS, blk, 0, stream>>>(
        A, nullptr, off, gn1w, gn1b, gn1ms, dinv, xh, A);

    // layer 2: gather(xh)+transform -> B ; GN + res(A) in-place -> x2=B (+ xh)
    k_gat32<<<ggrid4, blk, 0, stream>>>(xh, csr, rowptr, dinv, W2, b2, B);
    k_gn2<true, true><<<N_GRAPHS, blk, 0, stream>>>(
        B, A, off, gn2w, gn2b, gn2ms, dinv, xh, B);

    // layer 3: gather(xh)+transform -> A ; GN + res(B) + pool + linear -> out
    k_gat32<<<ggrid4, blk, 0, stream>>>(xh, csr, rowptr, dinv, W3, b3, A);
    k_gnfin<<<N_GRAPHS, blk, 0, stream>>>(A, B, off, gn3w, gn3b, gn3ms,
                                          lin_w, lin_b, out);
}